// Round 12
// baseline (1605.514 us; speedup 1.0000x reference)
//
#include <hip/hip_runtime.h>
#include <hip/hip_bf16.h>

// TinyLocalWindowAttention on MI355X (gfx950)
// x:(32,256,112,112) f32, 7x7 windows; ONE BLOCK = 4 horizontally-adjacent
// windows, processed sequentially with cross-window pipelining (grid 2048,
// 4 waves, LDS 48KB -> 3 blocks/CU, the measured L2 sweet spot).
// Per window: wave h computes its own head's q/k/v (R11 structure, all
// attention fragments built in registers via ds_bpermute); proj output is
// stored DIRECTLY from registers as f32 (no out_s LDS round trip).
// Window w+1's x loads are issued after window w's qkv frees the xa buffer
// and staged to LDS after attention -> load latency hidden (T14 split).

typedef short bf16x8 __attribute__((ext_vector_type(8)));   // 8 bf16 (4 VGPRs)
typedef float f32x4 __attribute__((ext_vector_type(4)));

static __device__ __forceinline__ unsigned int cvt2(float a, float b) {
    float2 t; t.x = a; t.y = b;
    __hip_bfloat162 hh = __float22bfloat162_rn(t);
    unsigned int u; __builtin_memcpy(&u, &hh, 4); return u;
}

#define WQ_ELEMS 65536LL
#define WP_ELEMS 32768LL

// ---- pre-pass: Wqkv[256][256], Wproj[128][256] f32 -> bf16 fragment arrays.
// frag[((tile*KT+kt)*64+lane)*8+j] = W[kt*32+(lane>>4)*8+j][tile*16+(lane&15)]
__global__ void prep_weights(const float* __restrict__ Wqkv,
                             const float* __restrict__ Wproj,
                             unsigned short* __restrict__ wq,
                             unsigned short* __restrict__ wp) {
    int tid = blockIdx.x * 256 + threadIdx.x;
    if (tid < 8192) {                         // 16 tiles * 8 ktiles * 64 lanes
        int lane = tid & 63, f = tid >> 6;
        int kt = f & 7, nt = f >> 3;
        int kbase = kt * 32 + (lane >> 4) * 8;
        int col = nt * 16 + (lane & 15);
        uint4 u;
        u.x = cvt2(Wqkv[(kbase + 0) * 256 + col], Wqkv[(kbase + 1) * 256 + col]);
        u.y = cvt2(Wqkv[(kbase + 2) * 256 + col], Wqkv[(kbase + 3) * 256 + col]);
        u.z = cvt2(Wqkv[(kbase + 4) * 256 + col], Wqkv[(kbase + 5) * 256 + col]);
        u.w = cvt2(Wqkv[(kbase + 6) * 256 + col], Wqkv[(kbase + 7) * 256 + col]);
        *reinterpret_cast<uint4*>(&wq[(long long)tid * 8]) = u;
    } else if (tid < 12288) {                 // 16 tiles * 4 ktiles * 64 lanes
        int i2 = tid - 8192;
        int lane = i2 & 63, f = i2 >> 6;
        int kt = f & 3, nt = f >> 2;
        int kbase = kt * 32 + (lane >> 4) * 8;
        int col = nt * 16 + (lane & 15);
        uint4 u;
        u.x = cvt2(Wproj[(kbase + 0) * 256 + col], Wproj[(kbase + 1) * 256 + col]);
        u.y = cvt2(Wproj[(kbase + 2) * 256 + col], Wproj[(kbase + 3) * 256 + col]);
        u.z = cvt2(Wproj[(kbase + 4) * 256 + col], Wproj[(kbase + 5) * 256 + col]);
        u.w = cvt2(Wproj[(kbase + 6) * 256 + col], Wproj[(kbase + 7) * 256 + col]);
        *reinterpret_cast<uint4*>(&wp[(long long)i2 * 8]) = u;
    }
}

// LDS: static A (32KB): xa[64][256] (per current window; re-staged per window)
//      dynamic OS (16KB): o_s[64][128]
// swizzle: elem(row,col,W) = row*W + (((col>>3) ^ (row&7))<<3) + (col&7)

__global__ __launch_bounds__(256, 3) void win_attn(
    const float* __restrict__ x,
    const unsigned short* __restrict__ wfq,
    const unsigned short* __restrict__ wfp,
    const float* __restrict__ bqkv,
    const float* __restrict__ bproj,
    float* __restrict__ out)
{
    __shared__ __align__(16) unsigned short A[16384];
    extern __shared__ unsigned short OS[];    // 16 KB: o_s[64][128]

    const int tid  = threadIdx.x;
    const int lane = tid & 63;
    const int wave = tid >> 6;
    const int lr   = lane & 15;       // row/col within 16-tile
    const int kg   = lane >> 4;       // k-group (0..3)
    const int h    = wave;            // head

    // block -> 4 adjacent windows: lin = (b, wh, wq); window col = wq*4 + w
    const int bid = (int)blockIdx.x;
    const int lin = (bid & 7) * 256 + (bid >> 3);   // XCD-contiguous
    const int b   = lin >> 6;
    const int rem = lin & 63;
    const int wh  = rem >> 2;
    const int wq  = rem & 3;
    const int xbase = (b * 256) * 12544 + (wh * 7) * 112 + wq * 28;
    const int loff  = (lane / 7) * 112 + (lane % 7);   // token geometry (lane<49)

    // biases: q/k swapped (4 consecutive channels/lane); v unswapped; proj float4
    const float4 bq = *reinterpret_cast<const float4*>(&bqkv[h * 16 + kg * 4]);
    const float4 bk = *reinterpret_cast<const float4*>(&bqkv[64 + h * 16 + kg * 4]);
    const float bv0 = bqkv[128 + h * 32 + lr];
    const float bv1 = bqkv[128 + h * 32 + 16 + lr];
    float bpf[4][4];
    #pragma unroll
    for (int i = 0; i < 4; ++i) {
        const float4 t = *reinterpret_cast<const float4*>(&bproj[wave * 64 + i * 16 + kg * 4]);
        bpf[i][0] = t.x; bpf[i][1] = t.y; bpf[i][2] = t.z; bpf[i][3] = t.w;
    }

    // zero-pad token rows 49..63 ONCE (staging never touches them)
    {
        uint4 z4 = uint4{0u, 0u, 0u, 0u};
        for (int i = tid; i < 480; i += 256)
            reinterpret_cast<uint4*>(&A[49 * 256])[i] = z4;
    }
    // prologue: stage window 0
    if (lane < 49) {
        const int lb = xbase + loff;
        #pragma unroll 4
        for (int it = 0; it < 16; ++it) {
            const int c0 = wave * 64 + it * 4;
            const float v0 = x[lb + (c0 + 0) * 12544];
            const float v1 = x[lb + (c0 + 1) * 12544];
            const float v2 = x[lb + (c0 + 2) * 12544];
            const float v3 = x[lb + (c0 + 3) * 12544];
            uint2 pk; pk.x = cvt2(v0, v1); pk.y = cvt2(v2, v3);
            const int e = lane * 256 + (((c0 >> 3) ^ (lane & 7)) << 3) + (c0 & 7);
            *reinterpret_cast<uint2*>(&A[e]) = pk;
        }
    }

    const int a0 = (((kg & 1) * 2) * 16 + lr) * 4;
    const int a1 = (((kg & 1) * 2 + 1) * 16 + lr) * 4;
    const bool act = (lane < 32);
    const bf16x8 zf = {0, 0, 0, 0, 0, 0, 0, 0};
    const float C = 0.25f * 1.44269504f;    // SCALE * log2(e)

    #pragma unroll 1
    for (int w = 0; w < 4; ++w) {
        __syncthreads();   // B_xa: current window's xa ready

        // ---- qkv for THIS head: tiles tq=h, tk=4+h, tv0=8+2h, tv1=9+2h ----
        f32x4 aq[4], ak[4], av[4][2];
        #pragma unroll
        for (int t = 0; t < 4; ++t) {
            aq[t] = f32x4{0.f, 0.f, 0.f, 0.f};
            ak[t] = f32x4{0.f, 0.f, 0.f, 0.f};
            av[t][0] = f32x4{0.f, 0.f, 0.f, 0.f};
            av[t][1] = f32x4{0.f, 0.f, 0.f, 0.f};
        }
        {
            const int tq = h, tk = 4 + h, tv0 = 8 + 2 * h, tv1 = 9 + 2 * h;
            #pragma unroll
            for (int kt = 0; kt < 8; ++kt) {
                bf16x8 a[4];
                #pragma unroll
                for (int m = 0; m < 4; ++m) {
                    const int row = lr + 16 * m;
                    const int ch  = (kt * 4 + kg) ^ (row & 7);
                    a[m] = *reinterpret_cast<const bf16x8*>(&A[row * 256 + ch * 8]);
                }
                const bf16x8 bwq = *reinterpret_cast<const bf16x8*>(&wfq[((tq * 8 + kt) * 64 + lane) * 8]);
                const bf16x8 bwk = *reinterpret_cast<const bf16x8*>(&wfq[((tk * 8 + kt) * 64 + lane) * 8]);
                const bf16x8 bw0 = *reinterpret_cast<const bf16x8*>(&wfq[((tv0 * 8 + kt) * 64 + lane) * 8]);
                const bf16x8 bw1 = *reinterpret_cast<const bf16x8*>(&wfq[((tv1 * 8 + kt) * 64 + lane) * 8]);
                #pragma unroll
                for (int t = 0; t < 4; ++t) {
                    aq[t] = __builtin_amdgcn_mfma_f32_16x16x32_bf16(bwq, a[t], aq[t], 0, 0, 0);
                    ak[t] = __builtin_amdgcn_mfma_f32_16x16x32_bf16(bwk, a[t], ak[t], 0, 0, 0);
                    av[t][0] = __builtin_amdgcn_mfma_f32_16x16x32_bf16(a[t], bw0, av[t][0], 0, 0, 0);
                    av[t][1] = __builtin_amdgcn_mfma_f32_16x16x32_bf16(a[t], bw1, av[t][1], 0, 0, 0);
                }
            }
        }
        __syncthreads();   // B_Afree: all waves done reading xa

        // ---- issue next window's x loads (first half) -> hidden under attention
        float xr[8][4];
        const int lbn = xbase + (w + 1) * 7 + loff;
        if (w < 3 && lane < 49) {
            #pragma unroll
            for (int it = 0; it < 8; ++it) {
                const int c0 = wave * 64 + it * 4;
                xr[it][0] = x[lbn + (c0 + 0) * 12544];
                xr[it][1] = x[lbn + (c0 + 1) * 12544];
                xr[it][2] = x[lbn + (c0 + 2) * 12544];
                xr[it][3] = x[lbn + (c0 + 3) * 12544];
            }
        }

        // ---- in-register fragment builds (bpermute; no LDS) ----
        bf16x8 qf[4], kf[4];
        #pragma unroll
        for (int t = 0; t < 4; ++t) {
            const unsigned int d0 = cvt2(aq[t][0] + bq.x, aq[t][1] + bq.y);
            const unsigned int d1 = cvt2(aq[t][2] + bq.z, aq[t][3] + bq.w);
            union { unsigned int u[4]; bf16x8 v; } f;
            f.u[0] = (unsigned)__builtin_amdgcn_ds_bpermute(a0, (int)d0);
            f.u[1] = (unsigned)__builtin_amdgcn_ds_bpermute(a0, (int)d1);
            f.u[2] = (unsigned)__builtin_amdgcn_ds_bpermute(a1, (int)d0);
            f.u[3] = (unsigned)__builtin_amdgcn_ds_bpermute(a1, (int)d1);
            qf[t] = act ? f.v : zf;
        }
        #pragma unroll
        for (int t = 0; t < 4; ++t) {
            const unsigned int d0 = cvt2(ak[t][0] + bk.x, ak[t][1] + bk.y);
            const unsigned int d1 = cvt2(ak[t][2] + bk.z, ak[t][3] + bk.w);
            union { unsigned int u[4]; bf16x8 v; } f;
            f.u[0] = (unsigned)__builtin_amdgcn_ds_bpermute(a0, (int)d0);
            f.u[1] = (unsigned)__builtin_amdgcn_ds_bpermute(a0, (int)d1);
            f.u[2] = (unsigned)__builtin_amdgcn_ds_bpermute(a1, (int)d0);
            f.u[3] = (unsigned)__builtin_amdgcn_ds_bpermute(a1, (int)d1);
            kf[t] = act ? f.v : zf;
        }
        bf16x8 vb[2][2];
        {
            unsigned int ve0[4][2], ve1[4][2];
            #pragma unroll
            for (int tm = 0; tm < 4; ++tm)
                #pragma unroll
                for (int cn = 0; cn < 2; ++cn) {
                    const float bv = cn ? bv1 : bv0;
                    ve0[tm][cn] = cvt2(av[tm][cn][0] + bv, av[tm][cn][1] + bv);
                    ve1[tm][cn] = cvt2(av[tm][cn][2] + bv, av[tm][cn][3] + bv);
                }
            const bool lo2 = (kg < 2);
            #pragma unroll
            for (int kt = 0; kt < 2; ++kt)
                #pragma unroll
                for (int nt = 0; nt < 2; ++nt) {
                    const int ta = 2 * kt, tb = 2 * kt + 1;
                    const unsigned int u0a = (unsigned)__builtin_amdgcn_ds_bpermute(a0, (int)ve0[ta][nt]);
                    const unsigned int u0b = (unsigned)__builtin_amdgcn_ds_bpermute(a0, (int)ve0[tb][nt]);
                    const unsigned int u1a = (unsigned)__builtin_amdgcn_ds_bpermute(a0, (int)ve1[ta][nt]);
                    const unsigned int u1b = (unsigned)__builtin_amdgcn_ds_bpermute(a0, (int)ve1[tb][nt]);
                    const unsigned int u2a = (unsigned)__builtin_amdgcn_ds_bpermute(a1, (int)ve0[ta][nt]);
                    const unsigned int u2b = (unsigned)__builtin_amdgcn_ds_bpermute(a1, (int)ve0[tb][nt]);
                    const unsigned int u3a = (unsigned)__builtin_amdgcn_ds_bpermute(a1, (int)ve1[ta][nt]);
                    const unsigned int u3b = (unsigned)__builtin_amdgcn_ds_bpermute(a1, (int)ve1[tb][nt]);
                    union { unsigned int u[4]; bf16x8 v; } f;
                    f.u[0] = lo2 ? u0a : u0b;
                    f.u[1] = lo2 ? u1a : u1b;
                    f.u[2] = lo2 ? u2a : u2b;
                    f.u[3] = lo2 ? u3a : u3b;
                    vb[kt][nt] = f.v;
                }
        }

        // ---- attention: S^T = mfma(K,Q); in-register softmax; PV swapped ----
        f32x4 oacc[4][2];
        #pragma unroll
        for (int qn = 0; qn < 4; ++qn) {
            oacc[qn][0] = f32x4{0.f, 0.f, 0.f, 0.f};
            oacc[qn][1] = f32x4{0.f, 0.f, 0.f, 0.f};
        }
        float rsv[4];
        #pragma unroll
        for (int qn = 0; qn < 4; ++qn) {
            f32x4 s[4];
            #pragma unroll
            for (int km = 0; km < 4; ++km) {
                f32x4 z = f32x4{0.f, 0.f, 0.f, 0.f};
                s[km] = __builtin_amdgcn_mfma_f32_16x16x32_bf16(kf[km], qf[qn], z, 0, 0, 0);
            }
            float e[4][4];
            float sum = 0.f;
            #pragma unroll
            for (int km = 0; km < 4; ++km)
                #pragma unroll
                for (int r = 0; r < 4; ++r) {
                    float v = __builtin_amdgcn_exp2f(s[km][r] * C);
                    if (km == 3 && !(kg == 0 && r == 0)) v = 0.f;   // k-token 48 only
                    e[km][r] = v;
                    sum += v;
                }
            unsigned int D[4][2];
            #pragma unroll
            for (int km = 0; km < 4; ++km) {
                D[km][0] = cvt2(e[km][0], e[km][1]);
                D[km][1] = cvt2(e[km][2], e[km][3]);
            }
            sum += __shfl_xor(sum, 16, 64);
            sum += __shfl_xor(sum, 32, 64);
            rsv[qn] = __builtin_amdgcn_rcpf(sum);

            #pragma unroll
            for (int kt = 0; kt < 2; ++kt) {
                const int klo = 2 * kt, khi = 2 * kt + 1;
                const unsigned int t0 = (unsigned)__builtin_amdgcn_ds_bpermute(a0, (int)D[klo][0]);
                const unsigned int u0 = (unsigned)__builtin_amdgcn_ds_bpermute(a0, (int)D[khi][0]);
                const unsigned int t1 = (unsigned)__builtin_amdgcn_ds_bpermute(a0, (int)D[klo][1]);
                const unsigned int u1 = (unsigned)__builtin_amdgcn_ds_bpermute(a0, (int)D[khi][1]);
                const unsigned int t2 = (unsigned)__builtin_amdgcn_ds_bpermute(a1, (int)D[klo][0]);
                const unsigned int u2 = (unsigned)__builtin_amdgcn_ds_bpermute(a1, (int)D[khi][0]);
                const unsigned int t3 = (unsigned)__builtin_amdgcn_ds_bpermute(a1, (int)D[klo][1]);
                const unsigned int u3 = (unsigned)__builtin_amdgcn_ds_bpermute(a1, (int)D[khi][1]);
                union { unsigned int u[4]; bf16x8 v; } pu;
                pu.u[0] = (kg < 2) ? t0 : u0;
                pu.u[1] = (kg < 2) ? t1 : u1;
                pu.u[2] = (kg < 2) ? t2 : u2;
                pu.u[3] = (kg < 2) ? t3 : u3;
                oacc[qn][0] = __builtin_amdgcn_mfma_f32_16x16x32_bf16(vb[kt][0], pu.v, oacc[qn][0], 0, 0, 0);
                oacc[qn][1] = __builtin_amdgcn_mfma_f32_16x16x32_bf16(vb[kt][1], pu.v, oacc[qn][1], 0, 0, 0);
            }
        }

        // o_s[64][128] in OS: tok=qn*16+lr, c = h*32+nt*16+kg*4(+r)
        #pragma unroll
        for (int qn = 0; qn < 4; ++qn) {
            const float rs = rsv[qn];
            const int tok = qn * 16 + lr;
            #pragma unroll
            for (int nt = 0; nt < 2; ++nt) {
                const int cch = h * 4 + nt * 2 + (kg >> 1);
                const int clo = (kg & 1) * 4;
                uint2 pk;
                pk.x = cvt2(oacc[qn][nt][0] * rs, oacc[qn][nt][1] * rs);
                pk.y = cvt2(oacc[qn][nt][2] * rs, oacc[qn][nt][3] * rs);
                *reinterpret_cast<uint2*>(
                    &OS[tok * 128 + ((cch ^ (tok & 7)) << 3) + clo]) = pk;
            }
        }

        // ---- stage next window's xa into A (loads long since issued) ----
        if (w < 3 && lane < 49) {
            #pragma unroll
            for (int it = 0; it < 8; ++it) {
                const int c0 = wave * 64 + it * 4;
                uint2 pk;
                pk.x = cvt2(xr[it][0], xr[it][1]);
                pk.y = cvt2(xr[it][2], xr[it][3]);
                const int e = lane * 256 + (((c0 >> 3) ^ (lane & 7)) << 3) + (c0 & 7);
                *reinterpret_cast<uint2*>(&A[e]) = pk;
            }
            #pragma unroll
            for (int it = 8; it < 16; ++it) {
                const int c0 = wave * 64 + it * 4;
                const float v0 = x[lbn + (c0 + 0) * 12544];
                const float v1 = x[lbn + (c0 + 1) * 12544];
                const float v2 = x[lbn + (c0 + 2) * 12544];
                const float v3 = x[lbn + (c0 + 3) * 12544];
                uint2 pk; pk.x = cvt2(v0, v1); pk.y = cvt2(v2, v3);
                const int e = lane * 256 + (((c0 >> 3) ^ (lane & 7)) << 3) + (c0 & 7);
                *reinterpret_cast<uint2*>(&A[e]) = pk;
            }
        }
        __syncthreads();   // B_os: o_s ready (and staging ordered before next B_xa)

        // ---- proj (swapped): OUT^T = mfma(Wp-tile(ci), o-tile(tj)) ----
        f32x4 pc[4][4];
        #pragma unroll
        for (int m = 0; m < 4; ++m)
            #pragma unroll
            for (int nn = 0; nn < 4; ++nn)
                pc[m][nn] = f32x4{0.f, 0.f, 0.f, 0.f};

        #pragma unroll
        for (int kt = 0; kt < 4; ++kt) {
            bf16x8 a[4], bw[4];
            #pragma unroll
            for (int tj = 0; tj < 4; ++tj) {
                const int row = lr + 16 * tj;
                const int ch = (kt * 4 + kg) ^ (row & 7);
                a[tj] = *reinterpret_cast<const bf16x8*>(&OS[row * 128 + ch * 8]);
            }
            #pragma unroll
            for (int ci = 0; ci < 4; ++ci) {
                const int nt = wave * 4 + ci;
                bw[ci] = *reinterpret_cast<const bf16x8*>(&wfp[((nt * 4 + kt) * 64 + lane) * 8]);
            }
            #pragma unroll
            for (int ci = 0; ci < 4; ++ci)
                #pragma unroll
                for (int tj = 0; tj < 4; ++tj)
                    pc[ci][tj] = __builtin_amdgcn_mfma_f32_16x16x32_bf16(bw[ci], a[tj], pc[ci][tj], 0, 0, 0);
        }

        // ---- direct f32 stores from pc: out[tok, c] ----
        #pragma unroll
        for (int ci = 0; ci < 4; ++ci) {
            float* opc = out + xbase + w * 7 + (wave * 64 + ci * 16 + kg * 4) * 12544;
            #pragma unroll
            for (int tj = 0; tj < 4; ++tj) {
                if (tj < 3 || lr == 0) {
                    const int tok = tj * 16 + lr;
                    const int trow = tok / 7;
                    const int tcol = tok - trow * 7;
                    float* op = opc + trow * 112 + tcol;
                    op[0]         = pc[ci][tj][0] + bpf[ci][0];
                    op[12544]     = pc[ci][tj][1] + bpf[ci][1];
                    op[2 * 12544] = pc[ci][tj][2] + bpf[ci][2];
                    op[3 * 12544] = pc[ci][tj][3] + bpf[ci][3];
                }
            }
        }
    }
}

extern "C" void kernel_launch(void* const* d_in, const int* in_sizes, int n_in,
                              void* d_out, int out_size, void* d_ws, size_t ws_size,
                              hipStream_t stream) {
    const float* x     = (const float*)d_in[0];
    const float* Wqkv  = (const float*)d_in[1];
    const float* bqkv  = (const float*)d_in[2];
    const float* Wproj = (const float*)d_in[3];
    const float* bproj = (const float*)d_in[4];
    float* out = (float*)d_out;

    unsigned short* wfq = (unsigned short*)d_ws;
    unsigned short* wfp = wfq + WQ_ELEMS;

    prep_weights<<<48, 256, 0, stream>>>(Wqkv, Wproj, wfq, wfp);
    // 16 KB dynamic LDS = o_s; total 48 KB -> exactly 3 blocks/CU
    win_attn<<<2048, 256, 16384, stream>>>(x, wfq, wfp, bqkv, bproj, out);
}

// Round 13
// 487.296 us; speedup vs baseline: 3.2947x; 3.2947x over previous
//
#include <hip/hip_runtime.h>
#include <hip/hip_bf16.h>

// TinyLocalWindowAttention on MI355X (gfx950)
// x:(32,256,112,112) f32, 7x7 windows, 8192 windows; 1 block (4 waves) per window.
// bf16 MFMA 16x16x32.
// Round 13: R11 compute (own-head qkv, register fragments via ds_bpermute) +
// R9 A-overlay tail (o_s, out_s share the 32KB static buffer) -> LDS 32KB
// static + 8KB dynamic pad = 40KB -> EXACTLY 4 blocks/CU (16 waves, +33% TLP
// vs R11's 12). Clean occupancy probe: R3's 4-blk datapoint was confounded by
// its serialized softmax; 5-blk locality collapse (FETCH 830MB) is measured,
// 4-blk is not. Store/load code byte-identical to R11.

typedef short bf16x8 __attribute__((ext_vector_type(8)));   // 8 bf16 (4 VGPRs)
typedef float f32x4 __attribute__((ext_vector_type(4)));

static __device__ __forceinline__ unsigned int cvt2(float a, float b) {
    float2 t; t.x = a; t.y = b;
    __hip_bfloat162 hh = __float22bfloat162_rn(t);
    unsigned int u; __builtin_memcpy(&u, &hh, 4); return u;
}
static __device__ __forceinline__ float bf2f(unsigned int hs) {
    return __uint_as_float(hs << 16);
}

#define WQ_ELEMS 65536LL
#define WP_ELEMS 32768LL

// ---- pre-pass: Wqkv[256][256], Wproj[128][256] f32 -> bf16 fragment arrays.
// frag[((tile*KT+kt)*64+lane)*8+j] = W[kt*32+(lane>>4)*8+j][tile*16+(lane&15)]
__global__ void prep_weights(const float* __restrict__ Wqkv,
                             const float* __restrict__ Wproj,
                             unsigned short* __restrict__ wq,
                             unsigned short* __restrict__ wp) {
    int tid = blockIdx.x * 256 + threadIdx.x;
    if (tid < 8192) {                         // 16 tiles * 8 ktiles * 64 lanes
        int lane = tid & 63, f = tid >> 6;
        int kt = f & 7, nt = f >> 3;
        int kbase = kt * 32 + (lane >> 4) * 8;
        int col = nt * 16 + (lane & 15);
        uint4 u;
        u.x = cvt2(Wqkv[(kbase + 0) * 256 + col], Wqkv[(kbase + 1) * 256 + col]);
        u.y = cvt2(Wqkv[(kbase + 2) * 256 + col], Wqkv[(kbase + 3) * 256 + col]);
        u.z = cvt2(Wqkv[(kbase + 4) * 256 + col], Wqkv[(kbase + 5) * 256 + col]);
        u.w = cvt2(Wqkv[(kbase + 6) * 256 + col], Wqkv[(kbase + 7) * 256 + col]);
        *reinterpret_cast<uint4*>(&wq[(long long)tid * 8]) = u;
    } else if (tid < 12288) {                 // 16 tiles * 4 ktiles * 64 lanes
        int i2 = tid - 8192;
        int lane = i2 & 63, f = i2 >> 6;
        int kt = f & 3, nt = f >> 2;
        int kbase = kt * 32 + (lane >> 4) * 8;
        int col = nt * 16 + (lane & 15);
        uint4 u;
        u.x = cvt2(Wproj[(kbase + 0) * 256 + col], Wproj[(kbase + 1) * 256 + col]);
        u.y = cvt2(Wproj[(kbase + 2) * 256 + col], Wproj[(kbase + 3) * 256 + col]);
        u.z = cvt2(Wproj[(kbase + 4) * 256 + col], Wproj[(kbase + 5) * 256 + col]);
        u.w = cvt2(Wproj[(kbase + 6) * 256 + col], Wproj[(kbase + 7) * 256 + col]);
        *reinterpret_cast<uint4*>(&wp[(long long)i2 * 8]) = u;
    }
}

// LDS: static A (32KB): xa[64][256] -> o_s[64][128]@0 -> out_s[64][256]
//      + 8KB dynamic pad (occupancy control only) = 40KB -> 4 blocks/CU
// swizzle: elem(row,col,W) = row*W + (((col>>3) ^ (row&7))<<3) + (col&7)

__global__ __launch_bounds__(256, 4) void win_attn(
    const float* __restrict__ x,
    const unsigned short* __restrict__ wfq,
    const unsigned short* __restrict__ wfp,
    const float* __restrict__ bqkv,
    const float* __restrict__ bproj,
    float* __restrict__ out)
{
    __shared__ __align__(16) unsigned short A[16384];
    extern __shared__ unsigned short PAD[];   // 8KB pad, unused

    const int tid  = threadIdx.x;
    const int lane = tid & 63;
    const int wave = tid >> 6;
    const int lr   = lane & 15;       // row/col within 16-tile
    const int kg   = lane >> 4;       // k-group (0..3)
    const int h    = wave;            // head

    // XCD swizzle: contiguous 1024 windows per XCD
    const int bid = (int)blockIdx.x;
    const int L   = (bid & 7) * 1024 + (bid >> 3);
    const int b   = L >> 8;
    const int rem = L & 255;
    const int h0 = (rem >> 4) * 7;
    const int w0 = (rem & 15) * 7;
    const int xwin = (b * 256) * 12544 + h0 * 112 + w0;

    // biases: q/k swapped (4 consecutive channels/lane -> float4);
    // v unswapped (channel-in-tile = lr -> scalar); proj swapped (float4)
    const float4 bq = *reinterpret_cast<const float4*>(&bqkv[h * 16 + kg * 4]);
    const float4 bk = *reinterpret_cast<const float4*>(&bqkv[64 + h * 16 + kg * 4]);
    const float bv0 = bqkv[128 + h * 32 + lr];
    const float bv1 = bqkv[128 + h * 32 + 16 + lr];
    float4 bp4[4];
    #pragma unroll
    for (int i = 0; i < 4; ++i)
        bp4[i] = *reinterpret_cast<const float4*>(&bproj[wave * 64 + i * 16 + kg * 4]);

    // ---- phase A: zero pad rows 49..63, load x window -> xa (bf16) ----
    {
        uint4 z4 = uint4{0u, 0u, 0u, 0u};
        for (int i = tid; i < 480; i += 256)
            reinterpret_cast<uint4*>(&A[49 * 256])[i] = z4;
    }
    if (lane < 49) {
        const int lb = xwin + (lane / 7) * 112 + (lane % 7);
        #pragma unroll 4
        for (int it = 0; it < 16; ++it) {
            const int c0 = wave * 64 + it * 4;
            const float v0 = x[lb + (c0 + 0) * 12544];
            const float v1 = x[lb + (c0 + 1) * 12544];
            const float v2 = x[lb + (c0 + 2) * 12544];
            const float v3 = x[lb + (c0 + 3) * 12544];
            uint2 pk; pk.x = cvt2(v0, v1); pk.y = cvt2(v2, v3);
            const int e = lane * 256 + (((c0 >> 3) ^ (lane & 7)) << 3) + (c0 & 7);
            *reinterpret_cast<uint2*>(&A[e]) = pk;
        }
    }
    __syncthreads();   // B1: xa ready

    // ---- qkv for THIS head: tiles tq=h, tk=4+h, tv0=8+2h, tv1=9+2h ----
    // aq/ak swapped:  col=token, row=channel (lane holds 4 ch of token lr+16t)
    // av   unswapped: col=channel, row=token (lane holds 4 tok of ch lr)
    f32x4 aq[4], ak[4], av[4][2];
    #pragma unroll
    for (int t = 0; t < 4; ++t) {
        aq[t] = f32x4{0.f, 0.f, 0.f, 0.f};
        ak[t] = f32x4{0.f, 0.f, 0.f, 0.f};
        av[t][0] = f32x4{0.f, 0.f, 0.f, 0.f};
        av[t][1] = f32x4{0.f, 0.f, 0.f, 0.f};
    }
    {
        const int tq = h, tk = 4 + h, tv0 = 8 + 2 * h, tv1 = 9 + 2 * h;
        #pragma unroll
        for (int kt = 0; kt < 8; ++kt) {
            bf16x8 a[4];
            #pragma unroll
            for (int m = 0; m < 4; ++m) {
                const int row = lr + 16 * m;
                const int ch  = (kt * 4 + kg) ^ (row & 7);
                a[m] = *reinterpret_cast<const bf16x8*>(&A[row * 256 + ch * 8]);
            }
            const bf16x8 bwq = *reinterpret_cast<const bf16x8*>(&wfq[((tq * 8 + kt) * 64 + lane) * 8]);
            const bf16x8 bwk = *reinterpret_cast<const bf16x8*>(&wfq[((tk * 8 + kt) * 64 + lane) * 8]);
            const bf16x8 bw0 = *reinterpret_cast<const bf16x8*>(&wfq[((tv0 * 8 + kt) * 64 + lane) * 8]);
            const bf16x8 bw1 = *reinterpret_cast<const bf16x8*>(&wfq[((tv1 * 8 + kt) * 64 + lane) * 8]);
            #pragma unroll
            for (int t = 0; t < 4; ++t) {
                aq[t] = __builtin_amdgcn_mfma_f32_16x16x32_bf16(bwq, a[t], aq[t], 0, 0, 0);
                ak[t] = __builtin_amdgcn_mfma_f32_16x16x32_bf16(bwk, a[t], ak[t], 0, 0, 0);
                av[t][0] = __builtin_amdgcn_mfma_f32_16x16x32_bf16(a[t], bw0, av[t][0], 0, 0, 0);
                av[t][1] = __builtin_amdgcn_mfma_f32_16x16x32_bf16(a[t], bw1, av[t][1], 0, 0, 0);
            }
        }
    }
    __syncthreads();   // B2: all waves done reading xa (A free for o_s)

    // ---- in-register fragment builds (bpermute; no LDS memory) ----
    const int a0 = (((kg & 1) * 2) * 16 + lr) * 4;
    const int a1 = (((kg & 1) * 2 + 1) * 16 + lr) * 4;
    const bool act = (lane < 32);
    const bf16x8 zf = {0, 0, 0, 0, 0, 0, 0, 0};

    bf16x8 qf[4], kf[4];
    #pragma unroll
    for (int t = 0; t < 4; ++t) {
        const unsigned int d0 = cvt2(aq[t][0] + bq.x, aq[t][1] + bq.y);
        const unsigned int d1 = cvt2(aq[t][2] + bq.z, aq[t][3] + bq.w);
        union { unsigned int u[4]; bf16x8 v; } f;
        f.u[0] = (unsigned)__builtin_amdgcn_ds_bpermute(a0, (int)d0);
        f.u[1] = (unsigned)__builtin_amdgcn_ds_bpermute(a0, (int)d1);
        f.u[2] = (unsigned)__builtin_amdgcn_ds_bpermute(a1, (int)d0);
        f.u[3] = (unsigned)__builtin_amdgcn_ds_bpermute(a1, (int)d1);
        qf[t] = act ? f.v : zf;
    }
    #pragma unroll
    for (int t = 0; t < 4; ++t) {
        const unsigned int d0 = cvt2(ak[t][0] + bk.x, ak[t][1] + bk.y);
        const unsigned int d1 = cvt2(ak[t][2] + bk.z, ak[t][3] + bk.w);
        union { unsigned int u[4]; bf16x8 v; } f;
        f.u[0] = (unsigned)__builtin_amdgcn_ds_bpermute(a0, (int)d0);
        f.u[1] = (unsigned)__builtin_amdgcn_ds_bpermute(a0, (int)d1);
        f.u[2] = (unsigned)__builtin_amdgcn_ds_bpermute(a1, (int)d0);
        f.u[3] = (unsigned)__builtin_amdgcn_ds_bpermute(a1, (int)d1);
        kf[t] = act ? f.v : zf;
    }
    bf16x8 vb[2][2];
    {
        unsigned int ve0[4][2], ve1[4][2];
        #pragma unroll
        for (int tm = 0; tm < 4; ++tm)
            #pragma unroll
            for (int cn = 0; cn < 2; ++cn) {
                const float bv = cn ? bv1 : bv0;
                ve0[tm][cn] = cvt2(av[tm][cn][0] + bv, av[tm][cn][1] + bv);
                ve1[tm][cn] = cvt2(av[tm][cn][2] + bv, av[tm][cn][3] + bv);
            }
        const bool lo2 = (kg < 2);
        #pragma unroll
        for (int kt = 0; kt < 2; ++kt)
            #pragma unroll
            for (int nt = 0; nt < 2; ++nt) {
                const int ta = 2 * kt, tb = 2 * kt + 1;
                const unsigned int u0a = (unsigned)__builtin_amdgcn_ds_bpermute(a0, (int)ve0[ta][nt]);
                const unsigned int u0b = (unsigned)__builtin_amdgcn_ds_bpermute(a0, (int)ve0[tb][nt]);
                const unsigned int u1a = (unsigned)__builtin_amdgcn_ds_bpermute(a0, (int)ve1[ta][nt]);
                const unsigned int u1b = (unsigned)__builtin_amdgcn_ds_bpermute(a0, (int)ve1[tb][nt]);
                const unsigned int u2a = (unsigned)__builtin_amdgcn_ds_bpermute(a1, (int)ve0[ta][nt]);
                const unsigned int u2b = (unsigned)__builtin_amdgcn_ds_bpermute(a1, (int)ve0[tb][nt]);
                const unsigned int u3a = (unsigned)__builtin_amdgcn_ds_bpermute(a1, (int)ve1[ta][nt]);
                const unsigned int u3b = (unsigned)__builtin_amdgcn_ds_bpermute(a1, (int)ve1[tb][nt]);
                union { unsigned int u[4]; bf16x8 v; } f;
                f.u[0] = lo2 ? u0a : u0b;
                f.u[1] = lo2 ? u1a : u1b;
                f.u[2] = lo2 ? u2a : u2b;
                f.u[3] = lo2 ? u3a : u3b;
                vb[kt][nt] = f.v;
            }
    }

    // ---- attention: S^T = mfma(K,Q); in-register softmax; PV swapped ----
    f32x4 oacc[4][2];
    #pragma unroll
    for (int qn = 0; qn < 4; ++qn) {
        oacc[qn][0] = f32x4{0.f, 0.f, 0.f, 0.f};
        oacc[qn][1] = f32x4{0.f, 0.f, 0.f, 0.f};
    }
    float rsv[4];
    const float C = 0.25f * 1.44269504f;    // SCALE * log2(e)

    #pragma unroll
    for (int qn = 0; qn < 4; ++qn) {
        f32x4 s[4];
        #pragma unroll
        for (int km = 0; km < 4; ++km) {
            f32x4 z = f32x4{0.f, 0.f, 0.f, 0.f};
            s[km] = __builtin_amdgcn_mfma_f32_16x16x32_bf16(kf[km], qf[qn], z, 0, 0, 0);
        }
        float e[4][4];
        float sum = 0.f;
        #pragma unroll
        for (int km = 0; km < 4; ++km)
            #pragma unroll
            for (int r = 0; r < 4; ++r) {
                float v = __builtin_amdgcn_exp2f(s[km][r] * C);
                if (km == 3 && !(kg == 0 && r == 0)) v = 0.f;   // k-token 48 only
                e[km][r] = v;
                sum += v;
            }
        unsigned int D[4][2];
        #pragma unroll
        for (int km = 0; km < 4; ++km) {
            D[km][0] = cvt2(e[km][0], e[km][1]);
            D[km][1] = cvt2(e[km][2], e[km][3]);
        }
        sum += __shfl_xor(sum, 16, 64);
        sum += __shfl_xor(sum, 32, 64);
        rsv[qn] = __builtin_amdgcn_rcpf(sum);

        #pragma unroll
        for (int kt = 0; kt < 2; ++kt) {
            const int klo = 2 * kt, khi = 2 * kt + 1;
            const unsigned int t0 = (unsigned)__builtin_amdgcn_ds_bpermute(a0, (int)D[klo][0]);
            const unsigned int u0 = (unsigned)__builtin_amdgcn_ds_bpermute(a0, (int)D[khi][0]);
            const unsigned int t1 = (unsigned)__builtin_amdgcn_ds_bpermute(a0, (int)D[klo][1]);
            const unsigned int u1 = (unsigned)__builtin_amdgcn_ds_bpermute(a0, (int)D[khi][1]);
            const unsigned int t2 = (unsigned)__builtin_amdgcn_ds_bpermute(a1, (int)D[klo][0]);
            const unsigned int u2 = (unsigned)__builtin_amdgcn_ds_bpermute(a1, (int)D[khi][0]);
            const unsigned int t3 = (unsigned)__builtin_amdgcn_ds_bpermute(a1, (int)D[klo][1]);
            const unsigned int u3 = (unsigned)__builtin_amdgcn_ds_bpermute(a1, (int)D[khi][1]);
            union { unsigned int u[4]; bf16x8 v; } pu;
            pu.u[0] = (kg < 2) ? t0 : u0;
            pu.u[1] = (kg < 2) ? t1 : u1;
            pu.u[2] = (kg < 2) ? t2 : u2;
            pu.u[3] = (kg < 2) ? t3 : u3;
            oacc[qn][0] = __builtin_amdgcn_mfma_f32_16x16x32_bf16(vb[kt][0], pu.v, oacc[qn][0], 0, 0, 0);
            oacc[qn][1] = __builtin_amdgcn_mfma_f32_16x16x32_bf16(vb[kt][1], pu.v, oacc[qn][1], 0, 0, 0);
        }
    }

    // o_s[64][128] @ A[0): packed b64: tok=qn*16+lr, c = h*32+nt*16+kg*4(+r)
    #pragma unroll
    for (int qn = 0; qn < 4; ++qn) {
        const float rs = rsv[qn];
        const int tok = qn * 16 + lr;
        #pragma unroll
        for (int nt = 0; nt < 2; ++nt) {
            const int cch = h * 4 + nt * 2 + (kg >> 1);      // c>>3
            const int clo = (kg & 1) * 4;                    // c&7
            uint2 pk;
            pk.x = cvt2(oacc[qn][nt][0] * rs, oacc[qn][nt][1] * rs);
            pk.y = cvt2(oacc[qn][nt][2] * rs, oacc[qn][nt][3] * rs);
            *reinterpret_cast<uint2*>(
                &A[tok * 128 + ((cch ^ (tok & 7)) << 3) + clo]) = pk;
        }
    }
    __syncthreads();   // B3: o_s ready

    // ---- proj (swapped): OUT^T = mfma(Wp-tile(ci), o-tile(tj)) ----
    f32x4 pc[4][4];
    #pragma unroll
    for (int m = 0; m < 4; ++m)
        #pragma unroll
        for (int nn = 0; nn < 4; ++nn)
            pc[m][nn] = f32x4{0.f, 0.f, 0.f, 0.f};

    #pragma unroll
    for (int kt = 0; kt < 4; ++kt) {
        bf16x8 a[4], bw[4];
        #pragma unroll
        for (int tj = 0; tj < 4; ++tj) {
            const int row = lr + 16 * tj;                    // token
            const int ch = (kt * 4 + kg) ^ (row & 7);
            a[tj] = *reinterpret_cast<const bf16x8*>(&A[row * 128 + ch * 8]);
        }
        #pragma unroll
        for (int ci = 0; ci < 4; ++ci) {
            const int nt = wave * 4 + ci;
            bw[ci] = *reinterpret_cast<const bf16x8*>(&wfp[((nt * 4 + kt) * 64 + lane) * 8]);
        }
        #pragma unroll
        for (int ci = 0; ci < 4; ++ci)
            #pragma unroll
            for (int tj = 0; tj < 4; ++tj)
                pc[ci][tj] = __builtin_amdgcn_mfma_f32_16x16x32_bf16(bw[ci], a[tj], pc[ci][tj], 0, 0, 0);
    }
    __syncthreads();   // B4: proj reads done -> out_s overlays all of A

    // out_s[64][256]: packed b64: tok=tj*16+lr, c = wave*64+ci*16+kg*4(+r)
    #pragma unroll
    for (int ci = 0; ci < 4; ++ci) {
        const int cch = wave * 8 + ci * 2 + (kg >> 1);       // c>>3, 0..31
        const int clo = (kg & 1) * 4;                        // c&7
        #pragma unroll
        for (int tj = 0; tj < 4; ++tj) {
            const int tok = tj * 16 + lr;
            uint2 pk;
            pk.x = cvt2(pc[ci][tj][0] + bp4[ci].x, pc[ci][tj][1] + bp4[ci].y);
            pk.y = cvt2(pc[ci][tj][2] + bp4[ci].z, pc[ci][tj][3] + bp4[ci].w);
            *reinterpret_cast<uint2*>(
                &A[tok * 256 + ((cch ^ (tok & 7)) << 3) + clo]) = pk;
        }
    }
    // wave-own cols below (writes cols [wave*64,+64), reads the same)
    __builtin_amdgcn_wave_barrier();

    // ---- store: same 7-contiguous-float pattern as the loads (wave-own cols) ----
    if (lane < 49) {
        const int lb = xwin + (lane / 7) * 112 + (lane % 7);
        #pragma unroll 4
        for (int it = 0; it < 16; ++it) {
            const int c0 = wave * 64 + it * 4;
            const int e = lane * 256 + (((c0 >> 3) ^ (lane & 7)) << 3) + (c0 & 7);
            const uint2 pk = *reinterpret_cast<const uint2*>(&A[e]);
            out[lb + (c0 + 0) * 12544] = bf2f(pk.x & 0xffffu);
            out[lb + (c0 + 1) * 12544] = bf2f(pk.x >> 16);
            out[lb + (c0 + 2) * 12544] = bf2f(pk.y & 0xffffu);
            out[lb + (c0 + 3) * 12544] = bf2f(pk.y >> 16);
        }
    }
}

extern "C" void kernel_launch(void* const* d_in, const int* in_sizes, int n_in,
                              void* d_out, int out_size, void* d_ws, size_t ws_size,
                              hipStream_t stream) {
    const float* x     = (const float*)d_in[0];
    const float* Wqkv  = (const float*)d_in[1];
    const float* bqkv  = (const float*)d_in[2];
    const float* Wproj = (const float*)d_in[3];
    const float* bproj = (const float*)d_in[4];
    float* out = (float*)d_out;

    unsigned short* wfq = (unsigned short*)d_ws;
    unsigned short* wfp = wfq + WQ_ELEMS;

    prep_weights<<<48, 256, 0, stream>>>(Wqkv, Wproj, wfq, wfp);
    // 8 KB dynamic LDS pad: static 32 KB + 8 KB = 40 KB -> exactly 4 blocks/CU
    win_attn<<<8192, 256, 8192, stream>>>(x, wfq, wfp, bqkv, bproj, out);
}